// Round 17
// baseline (545.849 us; speedup 1.0000x reference)
//
#include <hip/hip_runtime.h>
#include <hip/hip_bf16.h>

#define H 4
#define D 256
#define NEG_SLOPE 0.2f

typedef __attribute__((ext_vector_type(8))) _Float16 f16x8;
typedef __attribute__((ext_vector_type(4))) _Float16 f16x4;
typedef __attribute__((ext_vector_type(4))) float f32x4;

// ---- W -> fp16 in MFMA fragment order ----
template<int K>
__device__ __forceinline__ void cvt_wfrag_one(const float* __restrict__ W,
                                              _Float16* __restrict__ wfrag, int idx) {
    const int NKS = K / 32;
    if (idx >= 16 * NKS * 64) return;
    int l  = idx & 63;
    int ks = (idx >> 6) % NKS;
    int c16 = idx / (NKS * 64);
    int col = c16 * 16 + (l & 15);
    int k0  = ks * 32 + (l >> 4) * 8;
    const float* src = &W[(size_t)col * K + k0];
    float4 v0 = *(const float4*)src;
    float4 v1 = *(const float4*)(src + 4);
    f16x8 o = {(_Float16)v0.x, (_Float16)v0.y, (_Float16)v0.z, (_Float16)v0.w,
               (_Float16)v1.x, (_Float16)v1.y, (_Float16)v1.z, (_Float16)v1.w};
    *(f16x8*)&wfrag[(size_t)idx * 8] = o;
}

__global__ void k_cvt_wfrag0(const float* __restrict__ W, _Float16* __restrict__ wfrag) {
    cvt_wfrag_one<128>(W, wfrag, blockIdx.x * blockDim.x + threadIdx.x);
}

__global__ void k_cvt_wfrag_all(const float* __restrict__ w1, const float* __restrict__ w2,
                                const float* __restrict__ w3, const float* __restrict__ w4,
                                _Float16* __restrict__ wfrag) {
    const float* ws[4] = {w1, w2, w3, w4};
    int l = blockIdx.y;
    cvt_wfrag_one<256>(ws[l], wfrag + 128 * 256 + (size_t)l * 256 * 256,
                       blockIdx.x * blockDim.x + threadIdx.x);
}

// ---- MFMA GEMM v6: 4-way col split (1 head/block), 32KB LDS, XCD-pinned ----
template<int K, bool F32X>
__global__ __launch_bounds__(256) void k_gemm_mfma(
        const void* __restrict__ xin, const _Float16* __restrict__ wfrag,
        const float* __restrict__ att_src, const float* __restrict__ att_dst,
        _Float16* __restrict__ hmat, float* __restrict__ alpha_src,
        float* __restrict__ alpha_dst, int nrows, int nchunk) {
    const int NKS = K / 32;
    __shared__ _Float16 sw[4 * NKS * 64 * 8];
    int t = threadIdx.x;
    int w = t >> 6, l = t & 63;
    int r = l & 15, q = l >> 4;

    int bid = blockIdx.x;
    int nfull = (nchunk >> 3) << 3;
    int dmain = nfull * 4;
    int chunk, split;
    if (bid < dmain) {
        int j = bid >> 3;
        chunk = (bid & 7) + 8 * (j >> 2);
        split = j & 3;
    } else {
        int idx = bid - dmain;
        chunk = nfull + (idx >> 2);
        split = idx & 3;
    }
    int row0 = chunk * 64;

    {
        const uint4* wsrc = (const uint4*)(wfrag + (size_t)split * 4 * NKS * 64 * 8);
        uint4* wdst = (uint4*)sw;
        #pragma unroll
        for (int i = 0; i < NKS; ++i)
            wdst[i * 256 + t] = wsrc[i * 256 + t];
    }

    int gr_a = row0 + w * 16 + r;
    bool aok = (gr_a < nrows);
    f16x8 a[NKS];
    #pragma unroll
    for (int ks = 0; ks < NKS; ++ks) {
        if (aok) {
            if constexpr (F32X) {
                const float* xs = (const float*)xin + (size_t)gr_a * K + ks * 32 + q * 8;
                float4 v0 = *(const float4*)xs;
                float4 v1 = *(const float4*)(xs + 4);
                a[ks] = (f16x8){(_Float16)v0.x, (_Float16)v0.y, (_Float16)v0.z,
                                (_Float16)v0.w, (_Float16)v1.x, (_Float16)v1.y,
                                (_Float16)v1.z, (_Float16)v1.w};
            } else {
                a[ks] = *(const f16x8*)((const _Float16*)xin + (size_t)gr_a * K + ks * 32 + q * 8);
            }
        } else {
            a[ks] = (f16x8){0, 0, 0, 0, 0, 0, 0, 0};
        }
    }

    __syncthreads();

    f32x4 acc[4];
    #pragma unroll
    for (int cf = 0; cf < 4; ++cf) acc[cf] = (f32x4){0.f, 0.f, 0.f, 0.f};
    #pragma unroll
    for (int cf = 0; cf < 4; ++cf) {
        f16x8 b[NKS];
        #pragma unroll
        for (int ks = 0; ks < NKS; ++ks)
            b[ks] = *(f16x8*)&sw[(size_t)((cf * NKS + ks) * 64 + l) * 8];
        #pragma unroll
        for (int ks = 0; ks < NKS; ++ks)
            acc[cf] = __builtin_amdgcn_mfma_f32_16x16x32_f16(a[ks], b[ks], acc[cf], 0, 0, 0);
    }

    #pragma unroll
    for (int cf = 0; cf < 4; ++cf) {
        #pragma unroll
        for (int i = 0; i < 4; ++i) {
            int gr = row0 + w * 16 + q * 4 + i;
            if (gr < nrows)
                hmat[(size_t)gr * D + split * 64 + cf * 16 + r] = (_Float16)acc[cf][i];
        }
    }
    float asv[4], adv[4];
    #pragma unroll
    for (int cf = 0; cf < 4; ++cf) {
        asv[cf] = att_src[split * 64 + cf * 16 + r];
        adv[cf] = att_dst[split * 64 + cf * 16 + r];
    }
    #pragma unroll
    for (int i = 0; i < 4; ++i) {
        float ps = 0.f, pd = 0.f;
        #pragma unroll
        for (int cf = 0; cf < 4; ++cf) {
            ps += acc[cf][i] * asv[cf];
            pd += acc[cf][i] * adv[cf];
        }
        #pragma unroll
        for (int m = 1; m < 16; m <<= 1) {
            ps += __shfl_xor(ps, m);
            pd += __shfl_xor(pd, m);
        }
        int gr = row0 + w * 16 + q * 4 + i;
        if (r == 0 && gr < nrows) {
            alpha_src[gr * 4 + split] = ps;
            alpha_dst[gr * 4 + split] = pd;
        }
    }
}

// ---------------- CSR build (graph constant across layers) ----------------
__global__ void k_deg(const int* __restrict__ ei, int E, int E2, int* __restrict__ deg) {
    int e = blockIdx.x * blockDim.x + threadIdx.x;
    if (e >= E2) return;
    int de = (e < E) ? ei[E + e] : (e - E);
    atomicAdd(&deg[de], 1);
}

__global__ void k_scan_block(const int* __restrict__ deg, int* __restrict__ incl,
                             int* __restrict__ bsum, int n) {
    __shared__ int sd[256];
    int t = threadIdx.x;
    int i = blockIdx.x * 256 + t;
    int v = (i < n) ? deg[i] : 0;
    sd[t] = v;
    __syncthreads();
    for (int off = 1; off < 256; off <<= 1) {
        int add = (t >= off) ? sd[t - off] : 0;
        __syncthreads();
        sd[t] += add;
        __syncthreads();
    }
    if (i < n) incl[i] = sd[t];
    if (t == 255) bsum[blockIdx.x] = sd[255];
}

__global__ void k_scan_bsum(int* __restrict__ bsum, int nb) {
    __shared__ int sd[256];
    int t = threadIdx.x;
    int v = (t < nb) ? bsum[t] : 0;
    sd[t] = v;
    __syncthreads();
    for (int off = 1; off < 256; off <<= 1) {
        int add = (t >= off) ? sd[t - off] : 0;
        __syncthreads();
        sd[t] += add;
        __syncthreads();
    }
    if (t < nb) bsum[t] = sd[t] - v;
}

__global__ void k_rowptr(const int* __restrict__ incl, const int* __restrict__ deg,
                         const int* __restrict__ boff, int* __restrict__ row_ptr,
                         int* __restrict__ cursor, int n, int total) {
    int i = blockIdx.x * blockDim.x + threadIdx.x;
    if (i < n) {
        row_ptr[i] = incl[i] - deg[i] + boff[i >> 8];
        cursor[i] = 0;
    }
    if (i == 0) row_ptr[n] = total;
}

__global__ void k_scatter(const int* __restrict__ ei, int E, int E2,
                          const int* __restrict__ row_ptr, int* __restrict__ cursor,
                          int* __restrict__ csr_src) {
    int e = blockIdx.x * blockDim.x + threadIdx.x;
    if (e >= E2) return;
    int se, de;
    if (e < E) { se = ei[e]; de = ei[E + e]; }
    else       { se = e - E; de = se; }
    int pos = atomicAdd(&cursor[de], 1);
    csr_src[row_ptr[de] + pos] = se;
}

// ---- per-node edge weights (all 4 heads) + inverse sums ----
// ew layout [head][E2] (per-cg stream contiguous); spinv [node][4].
__global__ void k_edge(const int* __restrict__ row_ptr, const int* __restrict__ csr_src,
                       const float4* __restrict__ asp4, const float4* __restrict__ adp4,
                       float* __restrict__ ew, float4* __restrict__ spinv,
                       int E2, int n) {
    int node = blockIdx.x * blockDim.x + threadIdx.x;
    if (node >= n) return;
    float4 ad = adp4[node];
    int st = row_ptr[node], en = row_ptr[node + 1];
    float4 s = make_float4(0.f, 0.f, 0.f, 0.f);
    for (int i = st; i < en; ++i) {
        float4 as = asp4[csr_src[i]];
        float a; float4 w;
        a = as.x + ad.x; a = a > 0.f ? a : NEG_SLOPE * a; w.x = __expf(a);
        a = as.y + ad.y; a = a > 0.f ? a : NEG_SLOPE * a; w.y = __expf(a);
        a = as.z + ad.z; a = a > 0.f ? a : NEG_SLOPE * a; w.z = __expf(a);
        a = as.w + ad.w; a = a > 0.f ? a : NEG_SLOPE * a; w.w = __expf(a);
        ew[i]          = w.x;
        ew[E2 + i]     = w.y;
        ew[2 * E2 + i] = w.z;
        ew[3 * E2 + i] = w.w;
        s.x += w.x; s.y += w.y; s.z += w.z; s.w += w.w;
    }
    spinv[node] = make_float4(1.f / (s.x + 1e-16f), 1.f / (s.y + 1e-16f),
                              1.f / (s.z + 1e-16f), 1.f / (s.w + 1e-16f));
}

// ---- aggregation v8: channel-split (cg=bid&7 -> XCD), 4 nodes/wave,
// lane = node2*16 + e4*4 + cq. 16 independent gather chains/wave, no shuffles
// in loop. Per-XCD h working set = 3.2MB (L2-resident).
__global__ __launch_bounds__(256) void k_agg8(
        const _Float16* __restrict__ hmat,
        const int* __restrict__ row_ptr, const int* __restrict__ csr_src,
        const float* __restrict__ ew, const float* __restrict__ spinv,
        const float* __restrict__ bias, float* __restrict__ outf,
        _Float16* __restrict__ outx, int E2, int relu, int nrows) {
    int bid = blockIdx.x;
    int cg = bid & 7;
    int chunk = bid >> 3;
    int t = threadIdx.x;
    int w = t >> 6, lane = t & 63;
    int node2 = lane >> 4;          // 0..3
    int e4 = (lane >> 2) & 3;       // edge slot
    int cq = lane & 3;              // 8-channel quad within the 32-ch group
    int node = chunk * 16 + w * 4 + node2;
    if (node >= nrows) return;
    int head = cg >> 1;
    const float* ewp = ew + (size_t)head * E2;
    int st = row_ptr[node], en = row_ptr[node + 1];
    int deg = en - st;
    float acc[8] = {};
    for (int e = e4; e < deg; e += 4) {
        int li = st + e;
        int sn = csr_src[li];
        float wgt = ewp[li];
        f16x8 hv = *(const f16x8*)&hmat[(size_t)sn * D + cg * 32 + cq * 8];
        #pragma unroll
        for (int k = 0; k < 8; ++k) acc[k] += wgt * (float)hv[k];
    }
    // reduce over the 4 edge slots (lane bits 2..3)
    #pragma unroll
    for (int k = 0; k < 8; ++k) {
        acc[k] += __shfl_xor(acc[k], 4);
        acc[k] += __shfl_xor(acc[k], 8);
    }
    if (e4 == 0) {
        float sinv = spinv[node * 4 + head];
        float4 b0 = *(const float4*)&bias[cg * 32 + cq * 8];
        float4 b1 = *(const float4*)&bias[cg * 32 + cq * 8 + 4];
        float o[8];
        o[0] = acc[0] * sinv + b0.x; o[1] = acc[1] * sinv + b0.y;
        o[2] = acc[2] * sinv + b0.z; o[3] = acc[3] * sinv + b0.w;
        o[4] = acc[4] * sinv + b1.x; o[5] = acc[5] * sinv + b1.y;
        o[6] = acc[6] * sinv + b1.z; o[7] = acc[7] * sinv + b1.w;
        if (relu) {
            #pragma unroll
            for (int k = 0; k < 8; ++k) o[k] = fmaxf(o[k], 0.f);
        }
        if (outx) {
            f16x8 o8 = {(_Float16)o[0], (_Float16)o[1], (_Float16)o[2], (_Float16)o[3],
                        (_Float16)o[4], (_Float16)o[5], (_Float16)o[6], (_Float16)o[7]};
            *(f16x8*)&outx[(size_t)node * D + cg * 32 + cq * 8] = o8;
        } else {
            *(float4*)&outf[(size_t)node * D + cg * 32 + cq * 8] =
                make_float4(o[0], o[1], o[2], o[3]);
            *(float4*)&outf[(size_t)node * D + cg * 32 + cq * 8 + 4] =
                make_float4(o[4], o[5], o[6], o[7]);
        }
    }
}

extern "C" void kernel_launch(void* const* d_in, const int* in_sizes, int n_in,
                              void* d_out, int out_size, void* d_ws, size_t ws_size,
                              hipStream_t stream) {
    const float* x = (const float*)d_in[0];
    const int* ei = (const int*)d_in[1];
    const int N  = in_sizes[0] / 128;   // 50000
    const int E  = in_sizes[1] / 2;     // 400000
    const int E2 = E + N;               // + self loops

    char* wsp = (char*)d_ws;
    size_t off = 0;
    auto alloc = [&](size_t bytes) -> void* {
        void* p = wsp + off;
        off += (bytes + 255) & ~(size_t)255;
        return p;
    };
    _Float16* bufH  = (_Float16*)alloc((size_t)N * D * 2);     // 25.6 MB
    _Float16* xf16  = (_Float16*)alloc((size_t)N * D * 2);     // 25.6 MB
    _Float16* wfrag = (_Float16*)alloc((size_t)(128 * 256 + 4 * 256 * 256) * 2);
    float* alpha_src = (float*)alloc((size_t)N * H * 4);
    float* alpha_dst = (float*)alloc((size_t)N * H * 4);
    float* ew    = (float*)alloc((size_t)4 * E2 * 4);          // [head][E2], 7.2 MB
    float* spinv = (float*)alloc((size_t)N * 4 * 4);
    int*   deg      = (int*)alloc((size_t)N * 4);
    int*   incl     = (int*)alloc((size_t)N * 4);
    int*   bsum     = (int*)alloc(256 * 4);
    int*   row_ptr  = (int*)alloc((size_t)(N + 1) * 4);
    int*   cursor   = (int*)alloc((size_t)N * 4);
    int*   csr_src  = (int*)alloc((size_t)E2 * 4);
    (void)ws_size;

    hipMemsetAsync(deg, 0, (size_t)N * 4, stream);

    // W -> fragment layout
    k_cvt_wfrag0<<<(16 * 4 * 64 + 255) / 256, 256, 0, stream>>>(
        (const float*)d_in[2], wfrag);
    dim3 wg((16 * 8 * 64 + 255) / 256, 4);
    k_cvt_wfrag_all<<<wg, 256, 0, stream>>>(
        (const float*)d_in[6], (const float*)d_in[10],
        (const float*)d_in[14], (const float*)d_in[18], wfrag);

    // CSR by dst
    int egrid = (E2 + 255) / 256;
    k_deg<<<egrid, 256, 0, stream>>>(ei, E, E2, deg);
    int nb = (N + 255) / 256;
    k_scan_block<<<nb, 256, 0, stream>>>(deg, incl, bsum, N);
    k_scan_bsum<<<1, 256, 0, stream>>>(bsum, nb);
    k_rowptr<<<nb, 256, 0, stream>>>(incl, deg, bsum, row_ptr, cursor, N, E2);
    k_scatter<<<egrid, 256, 0, stream>>>(ei, E, E2, row_ptr, cursor, csr_src);

    int nchunk = (N + 63) / 64;
    int ngrid = (N + 255) / 256;
    int agrid = ((N + 15) / 16) * 8;    // node-chunks x 8 channel groups
    for (int l = 0; l < 5; ++l) {
        const float* as_ = (const float*)d_in[3 + 4 * l];
        const float* ad_ = (const float*)d_in[4 + 4 * l];
        const float* bs_ = (const float*)d_in[5 + 4 * l];
        const _Float16* wl = (l == 0) ? wfrag
                           : wfrag + 128 * 256 + (size_t)(l - 1) * 256 * 256;

        if (l == 0)
            k_gemm_mfma<128, true><<<nchunk * 4, 256, 0, stream>>>(
                x, wl, as_, ad_, bufH, alpha_src, alpha_dst, N, nchunk);
        else
            k_gemm_mfma<256, false><<<nchunk * 4, 256, 0, stream>>>(
                xf16, wl, as_, ad_, bufH, alpha_src, alpha_dst, N, nchunk);

        k_edge<<<ngrid, 256, 0, stream>>>(row_ptr, csr_src,
                                          (const float4*)alpha_src,
                                          (const float4*)alpha_dst,
                                          ew, (float4*)spinv, E2, N);

        int last = (l == 4);
        k_agg8<<<agrid, 256, 0, stream>>>(bufH, row_ptr, csr_src, ew, spinv, bs_,
                                          last ? (float*)d_out : nullptr,
                                          last ? nullptr : xf16,
                                          E2, last ? 0 : 1, N);
    }
}

// Round 18
// 374.088 us; speedup vs baseline: 1.4591x; 1.4591x over previous
//
#include <hip/hip_runtime.h>
#include <hip/hip_bf16.h>

#define H 4
#define D 256
#define NEG_SLOPE 0.2f

typedef __attribute__((ext_vector_type(8))) _Float16 f16x8;
typedef __attribute__((ext_vector_type(4))) _Float16 f16x4;
typedef __attribute__((ext_vector_type(4))) float f32x4;

// ---- W -> fp16 in MFMA fragment order ----
template<int K>
__device__ __forceinline__ void cvt_wfrag_one(const float* __restrict__ W,
                                              _Float16* __restrict__ wfrag, int idx) {
    const int NKS = K / 32;
    if (idx >= 16 * NKS * 64) return;
    int l  = idx & 63;
    int ks = (idx >> 6) % NKS;
    int c16 = idx / (NKS * 64);
    int col = c16 * 16 + (l & 15);
    int k0  = ks * 32 + (l >> 4) * 8;
    const float* src = &W[(size_t)col * K + k0];
    float4 v0 = *(const float4*)src;
    float4 v1 = *(const float4*)(src + 4);
    f16x8 o = {(_Float16)v0.x, (_Float16)v0.y, (_Float16)v0.z, (_Float16)v0.w,
               (_Float16)v1.x, (_Float16)v1.y, (_Float16)v1.z, (_Float16)v1.w};
    *(f16x8*)&wfrag[(size_t)idx * 8] = o;
}

__global__ void k_cvt_wfrag0(const float* __restrict__ W, _Float16* __restrict__ wfrag) {
    cvt_wfrag_one<128>(W, wfrag, blockIdx.x * blockDim.x + threadIdx.x);
}

__global__ void k_cvt_wfrag_all(const float* __restrict__ w1, const float* __restrict__ w2,
                                const float* __restrict__ w3, const float* __restrict__ w4,
                                _Float16* __restrict__ wfrag) {
    const float* ws[4] = {w1, w2, w3, w4};
    int l = blockIdx.y;
    cvt_wfrag_one<256>(ws[l], wfrag + 128 * 256 + (size_t)l * 256 * 256,
                       blockIdx.x * blockDim.x + threadIdx.x);
}

// ---- MFMA GEMM v6: 4-way col split (1 head/block), 32KB LDS, XCD-pinned ----
// bid%8 = XCD (round-robin); all 4 splits of a row-chunk map to the same XCD
// so the x re-reads are L2 hits. Wave = 16 rows x 64 cols, 4 cf accs.
template<int K, bool F32X>
__global__ __launch_bounds__(256) void k_gemm_mfma(
        const void* __restrict__ xin, const _Float16* __restrict__ wfrag,
        const float* __restrict__ att_src, const float* __restrict__ att_dst,
        _Float16* __restrict__ hmat, float* __restrict__ alpha_src,
        float* __restrict__ alpha_dst, int nrows, int nchunk) {
    const int NKS = K / 32;
    __shared__ _Float16 sw[4 * NKS * 64 * 8];          // 32KB (K=256) / 16KB (K=128)
    int t = threadIdx.x;
    int w = t >> 6, l = t & 63;
    int r = l & 15, q = l >> 4;

    // XCD-pinned (chunk, split) decode: chunk%8 == bid%8 for the main range
    int bid = blockIdx.x;
    int nfull = (nchunk >> 3) << 3;
    int dmain = nfull * 4;
    int chunk, split;
    if (bid < dmain) {
        int j = bid >> 3;
        chunk = (bid & 7) + 8 * (j >> 2);
        split = j & 3;
    } else {
        int idx = bid - dmain;
        chunk = nfull + (idx >> 2);
        split = idx & 3;
    }
    int row0 = chunk * 64;

    // stage this split's W fragments (4 col-frags x NKS) -> LDS
    {
        const uint4* wsrc = (const uint4*)(wfrag + (size_t)split * 4 * NKS * 64 * 8);
        uint4* wdst = (uint4*)sw;
        #pragma unroll
        for (int i = 0; i < NKS; ++i)
            wdst[i * 256 + t] = wsrc[i * 256 + t];
    }

    int gr_a = row0 + w * 16 + r;
    bool aok = (gr_a < nrows);
    f16x8 a[NKS];
    #pragma unroll
    for (int ks = 0; ks < NKS; ++ks) {
        if (aok) {
            if constexpr (F32X) {
                const float* xs = (const float*)xin + (size_t)gr_a * K + ks * 32 + q * 8;
                float4 v0 = *(const float4*)xs;
                float4 v1 = *(const float4*)(xs + 4);
                a[ks] = (f16x8){(_Float16)v0.x, (_Float16)v0.y, (_Float16)v0.z,
                                (_Float16)v0.w, (_Float16)v1.x, (_Float16)v1.y,
                                (_Float16)v1.z, (_Float16)v1.w};
            } else {
                a[ks] = *(const f16x8*)((const _Float16*)xin + (size_t)gr_a * K + ks * 32 + q * 8);
            }
        } else {
            a[ks] = (f16x8){0, 0, 0, 0, 0, 0, 0, 0};
        }
    }

    __syncthreads();

    f32x4 acc[4];
    #pragma unroll
    for (int cf = 0; cf < 4; ++cf) acc[cf] = (f32x4){0.f, 0.f, 0.f, 0.f};
    #pragma unroll
    for (int cf = 0; cf < 4; ++cf) {
        f16x8 b[NKS];
        #pragma unroll
        for (int ks = 0; ks < NKS; ++ks)
            b[ks] = *(f16x8*)&sw[(size_t)((cf * NKS + ks) * 64 + l) * 8];
        #pragma unroll
        for (int ks = 0; ks < NKS; ++ks)
            acc[cf] = __builtin_amdgcn_mfma_f32_16x16x32_f16(a[ks], b[ks], acc[cf], 0, 0, 0);
    }

    // store h: col = split*64 + cf*16 + r
    #pragma unroll
    for (int cf = 0; cf < 4; ++cf) {
        #pragma unroll
        for (int i = 0; i < 4; ++i) {
            int gr = row0 + w * 16 + q * 4 + i;
            if (gr < nrows)
                hmat[(size_t)gr * D + split * 64 + cf * 16 + r] = (_Float16)acc[cf][i];
        }
    }
    // fused alpha: this block's 64 cols == head `split`
    float asv[4], adv[4];
    #pragma unroll
    for (int cf = 0; cf < 4; ++cf) {
        asv[cf] = att_src[split * 64 + cf * 16 + r];
        adv[cf] = att_dst[split * 64 + cf * 16 + r];
    }
    #pragma unroll
    for (int i = 0; i < 4; ++i) {
        float ps = 0.f, pd = 0.f;
        #pragma unroll
        for (int cf = 0; cf < 4; ++cf) {
            ps += acc[cf][i] * asv[cf];
            pd += acc[cf][i] * adv[cf];
        }
        #pragma unroll
        for (int m = 1; m < 16; m <<= 1) {
            ps += __shfl_xor(ps, m);
            pd += __shfl_xor(pd, m);
        }
        int gr = row0 + w * 16 + q * 4 + i;
        if (r == 0 && gr < nrows) {
            alpha_src[gr * 4 + split] = ps;
            alpha_dst[gr * 4 + split] = pd;
        }
    }
}

// ---------------- CSR build (graph constant across layers) ----------------
__global__ void k_deg(const int* __restrict__ ei, int E, int E2, int* __restrict__ deg) {
    int e = blockIdx.x * blockDim.x + threadIdx.x;
    if (e >= E2) return;
    int de = (e < E) ? ei[E + e] : (e - E);
    atomicAdd(&deg[de], 1);
}

__global__ void k_scan_block(const int* __restrict__ deg, int* __restrict__ incl,
                             int* __restrict__ bsum, int n) {
    __shared__ int sd[256];
    int t = threadIdx.x;
    int i = blockIdx.x * 256 + t;
    int v = (i < n) ? deg[i] : 0;
    sd[t] = v;
    __syncthreads();
    for (int off = 1; off < 256; off <<= 1) {
        int add = (t >= off) ? sd[t - off] : 0;
        __syncthreads();
        sd[t] += add;
        __syncthreads();
    }
    if (i < n) incl[i] = sd[t];
    if (t == 255) bsum[blockIdx.x] = sd[255];
}

__global__ void k_scan_bsum(int* __restrict__ bsum, int nb) {
    __shared__ int sd[256];
    int t = threadIdx.x;
    int v = (t < nb) ? bsum[t] : 0;
    sd[t] = v;
    __syncthreads();
    for (int off = 1; off < 256; off <<= 1) {
        int add = (t >= off) ? sd[t - off] : 0;
        __syncthreads();
        sd[t] += add;
        __syncthreads();
    }
    if (t < nb) bsum[t] = sd[t] - v;
}

__global__ void k_rowptr(const int* __restrict__ incl, const int* __restrict__ deg,
                         const int* __restrict__ boff, int* __restrict__ row_ptr,
                         int* __restrict__ cursor, int n, int total) {
    int i = blockIdx.x * blockDim.x + threadIdx.x;
    if (i < n) {
        row_ptr[i] = incl[i] - deg[i] + boff[i >> 8];
        cursor[i] = 0;
    }
    if (i == 0) row_ptr[n] = total;
}

__global__ void k_scatter(const int* __restrict__ ei, int E, int E2,
                          const int* __restrict__ row_ptr, int* __restrict__ cursor,
                          int* __restrict__ csr_src) {
    int e = blockIdx.x * blockDim.x + threadIdx.x;
    if (e >= E2) return;
    int se, de;
    if (e < E) { se = ei[e]; de = ei[E + e]; }
    else       { se = e - E; de = se; }
    int pos = atomicAdd(&cursor[de], 1);
    csr_src[row_ptr[de] + pos] = se;
}

// ---- aggregation v5.1: 2 nodes/wave, 32 lanes/node, idx-prefetch pipeline ----
__global__ __launch_bounds__(256) void k_aggregate(const _Float16* __restrict__ hmat,
        const int* __restrict__ row_ptr, const int* __restrict__ csr_src,
        const float* __restrict__ alpha_src, const float* __restrict__ alpha_dst,
        const float* __restrict__ bias, float* __restrict__ outf,
        _Float16* __restrict__ outx, int relu, int nrows) {
    int wid  = (blockIdx.x * 256 + threadIdx.x) >> 6;
    int lane = threadIdx.x & 63;
    int node = wid * 2 + (lane >> 5);      // 2 nodes per wave
    if (node >= nrows) return;
    int c    = lane & 31;                  // channel octet: channels c*8..c*8+7
    int head = c >> 3;
    int st = row_ptr[node], en = row_ptr[node + 1];
    int deg = en - st;
    int nbatch = (deg + 7) >> 3;
    float a_d = alpha_dst[node * 4 + head];
    float acc[8] = {};
    float ssum = 0.f;
    int sn[8];
    #pragma unroll
    for (int j = 0; j < 8; ++j) {
        int li = st + (j < deg ? j : deg - 1);
        sn[j] = csr_src[li];
    }
    for (int b = 0; b < nbatch; ++b) {
        f16x8 hv[8];
        #pragma unroll
        for (int j = 0; j < 8; ++j)
            hv[j] = *(const f16x8*)&hmat[(size_t)sn[j] * D + c * 8];
        float as[8];
        #pragma unroll
        for (int j = 0; j < 8; ++j) as[j] = alpha_src[sn[j] * 4 + head];
        int sn2[8];
        if (b + 1 < nbatch) {
            #pragma unroll
            for (int j = 0; j < 8; ++j) {
                int e = (b + 1) * 8 + j;
                int li = st + (e < deg ? e : deg - 1);
                sn2[j] = csr_src[li];
            }
        }
        #pragma unroll
        for (int j = 0; j < 8; ++j) {
            float a = as[j] + a_d;
            a = a > 0.f ? a : NEG_SLOPE * a;
            float ex = (b * 8 + j < deg) ? __expf(a) : 0.f;
            ssum += ex;
            #pragma unroll
            for (int k = 0; k < 8; ++k) acc[k] += ex * (float)hv[j][k];
        }
        #pragma unroll
        for (int j = 0; j < 8; ++j) sn[j] = sn2[j];
    }
    float sinv = 1.f / (ssum + 1e-16f);
    float4 b0 = *(const float4*)&bias[c * 8];
    float4 b1 = *(const float4*)&bias[c * 8 + 4];
    float o[8];
    o[0] = acc[0] * sinv + b0.x; o[1] = acc[1] * sinv + b0.y;
    o[2] = acc[2] * sinv + b0.z; o[3] = acc[3] * sinv + b0.w;
    o[4] = acc[4] * sinv + b1.x; o[5] = acc[5] * sinv + b1.y;
    o[6] = acc[6] * sinv + b1.z; o[7] = acc[7] * sinv + b1.w;
    if (relu) {
        #pragma unroll
        for (int k = 0; k < 8; ++k) o[k] = fmaxf(o[k], 0.f);
    }
    if (outx) {
        f16x8 o8 = {(_Float16)o[0], (_Float16)o[1], (_Float16)o[2], (_Float16)o[3],
                    (_Float16)o[4], (_Float16)o[5], (_Float16)o[6], (_Float16)o[7]};
        *(f16x8*)&outx[(size_t)node * D + c * 8] = o8;
    } else {
        *(float4*)&outf[(size_t)node * D + c * 8] =
            make_float4(o[0], o[1], o[2], o[3]);
        *(float4*)&outf[(size_t)node * D + c * 8 + 4] =
            make_float4(o[4], o[5], o[6], o[7]);
    }
}

extern "C" void kernel_launch(void* const* d_in, const int* in_sizes, int n_in,
                              void* d_out, int out_size, void* d_ws, size_t ws_size,
                              hipStream_t stream) {
    const float* x = (const float*)d_in[0];
    const int* ei = (const int*)d_in[1];
    const int N  = in_sizes[0] / 128;   // 50000
    const int E  = in_sizes[1] / 2;     // 400000
    const int E2 = E + N;               // + self loops

    char* wsp = (char*)d_ws;
    size_t off = 0;
    auto alloc = [&](size_t bytes) -> void* {
        void* p = wsp + off;
        off += (bytes + 255) & ~(size_t)255;
        return p;
    };
    _Float16* bufH  = (_Float16*)alloc((size_t)N * D * 2);     // 25.6 MB
    _Float16* xf16  = (_Float16*)alloc((size_t)N * D * 2);     // 25.6 MB
    _Float16* wfrag = (_Float16*)alloc((size_t)(128 * 256 + 4 * 256 * 256) * 2);
    float* alpha_src = (float*)alloc((size_t)N * H * 4);
    float* alpha_dst = (float*)alloc((size_t)N * H * 4);
    int*   deg       = (int*)alloc((size_t)N * 4);
    int*   incl      = (int*)alloc((size_t)N * 4);
    int*   bsum      = (int*)alloc(256 * 4);
    int*   row_ptr   = (int*)alloc((size_t)(N + 1) * 4);
    int*   cursor    = (int*)alloc((size_t)N * 4);
    int*   csr_src   = (int*)alloc((size_t)E2 * 4);
    (void)ws_size;

    hipMemsetAsync(deg, 0, (size_t)N * 4, stream);

    // W -> fragment layout (layer 0 + merged layers 1-4)
    k_cvt_wfrag0<<<(16 * 4 * 64 + 255) / 256, 256, 0, stream>>>(
        (const float*)d_in[2], wfrag);
    dim3 wg((16 * 8 * 64 + 255) / 256, 4);
    k_cvt_wfrag_all<<<wg, 256, 0, stream>>>(
        (const float*)d_in[6], (const float*)d_in[10],
        (const float*)d_in[14], (const float*)d_in[18], wfrag);

    // CSR by dst
    int egrid = (E2 + 255) / 256;
    k_deg<<<egrid, 256, 0, stream>>>(ei, E, E2, deg);
    int nb = (N + 255) / 256;
    k_scan_block<<<nb, 256, 0, stream>>>(deg, incl, bsum, N);
    k_scan_bsum<<<1, 256, 0, stream>>>(bsum, nb);
    k_rowptr<<<nb, 256, 0, stream>>>(incl, deg, bsum, row_ptr, cursor, N, E2);
    k_scatter<<<egrid, 256, 0, stream>>>(ei, E, E2, row_ptr, cursor, csr_src);

    int nchunk = (N + 63) / 64;
    int ggrid = nchunk * 4;             // 4 col-splits (heads), XCD-pinned decode
    int agrid = (N + 7) / 8;            // 4 waves x 2 nodes per block
    for (int l = 0; l < 5; ++l) {
        const float* as_ = (const float*)d_in[3 + 4 * l];
        const float* ad_ = (const float*)d_in[4 + 4 * l];
        const float* bs_ = (const float*)d_in[5 + 4 * l];
        const _Float16* wl = (l == 0) ? wfrag
                           : wfrag + 128 * 256 + (size_t)(l - 1) * 256 * 256;

        if (l == 0)
            k_gemm_mfma<128, true><<<ggrid, 256, 0, stream>>>(x, wl, as_, ad_,
                                                        bufH, alpha_src, alpha_dst, N, nchunk);
        else
            k_gemm_mfma<256, false><<<ggrid, 256, 0, stream>>>(xf16, wl, as_, ad_,
                                                        bufH, alpha_src, alpha_dst, N, nchunk);

        int last = (l == 4);
        k_aggregate<<<agrid, 256, 0, stream>>>(bufH, row_ptr, csr_src,
                                               alpha_src, alpha_dst, bs_,
                                               last ? (float*)d_out : nullptr,
                                               last ? nullptr : xf16,
                                               last ? 0 : 1, N);
    }
}